// Round 4
// baseline (740.876 us; speedup 1.0000x reference)
//
#include <hip/hip_runtime.h>
#include <math.h>

// VQ-VAE eval forward: argmin distances + one-hot + gather + loss + perplexity.
// inputs: [128,1024,64] fp32, embedding: [512,64] fp32
// out: loss[1] | quantized[8388608] | perplexity[1] | encodings[67108864]
//
// R4: kill the LDS pipe bottleneck (R3: 17.2 GB ds_read = 330 us floor).
// Sweep reads e at WAVE-UNIFORM global addresses (scalar/broadcast loads,
// L1/L2-hot 128 KB) instead of per-lane LDS reads. x stays in 64 VGPRs.
// Outputs fused in-kernel; LDS now only 3 KB (hist+idx+red) -> 4 blocks/CU.

#define NK 512
#define ND 64
#define NROWS 131072
#define BLOCK 256
#define NBLOCKS (NROWS / BLOCK)   // 512

#define Q_OFF    1
#define PERP_OFF 8388609
#define ENC_OFF  8388610

typedef float vfloat2 __attribute__((ext_vector_type(2)));

__global__ __launch_bounds__(512) void vq_eknorm(const float* __restrict__ emb,
                                                 float* __restrict__ eknorm) {
    int c = threadIdx.x;   // 512 codes
    const float4* er = (const float4*)(emb + c * ND);
    float s0 = 0.f, s1 = 0.f, s2 = 0.f, s3 = 0.f;
    #pragma unroll
    for (int j = 0; j < ND / 4; ++j) {
        float4 v = er[j];
        s0 += v.x * v.x; s1 += v.y * v.y; s2 += v.z * v.z; s3 += v.w * v.w;
    }
    eknorm[c] = (s0 + s1) + (s2 + s3);
}

__global__ __launch_bounds__(BLOCK, 4) void vq_main(const float* __restrict__ x,
                                                    const float* __restrict__ emb,
                                                    const float* __restrict__ eknorm,
                                                    float* __restrict__ out,
                                                    int* __restrict__ g_counts,
                                                    float* __restrict__ g_loss) {
    __shared__ int   hist[NK];
    __shared__ int   idx_s[BLOCK];
    __shared__ float red[4];

    const int tid = threadIdx.x;
    hist[tid] = 0;
    hist[tid + 256] = 0;
    __syncthreads();   // hist zero visible before post-sweep atomics

    // ---- load my row into registers (one-time, lane-private) ----
    const int row = blockIdx.x * BLOCK + tid;
    float4 xr[16];
    const float4* xp = (const float4*)(x + (size_t)row * ND);
    #pragma unroll
    for (int j = 0; j < 16; ++j) xr[j] = xp[j];

    float xn0 = 0.f, xn1 = 0.f, xn2 = 0.f, xn3 = 0.f;
    #pragma unroll
    for (int j = 0; j < 16; ++j) {
        xn0 += xr[j].x * xr[j].x; xn1 += xr[j].y * xr[j].y;
        xn2 += xr[j].z * xr[j].z; xn3 += xr[j].w * xr[j].w;
    }
    const float xnorm = (xn0 + xn1) + (xn2 + xn3);

    // ---- argmin sweep: e read at wave-uniform addresses (scalar/broadcast) ----
    float dmin = INFINITY;
    int amin = 0;
    for (int c = 0; c < NK; c += 2) {
        const float* e0 = emb + c * ND;        // uniform pointer
        const float* e1 = e0 + ND;
        float a0 = 0.f, a1 = 0.f, a2 = 0.f, a3 = 0.f;
        float b0 = 0.f, b1 = 0.f, b2 = 0.f, b3 = 0.f;
        #pragma unroll
        for (int j = 0; j < 16; ++j) {
            float4 xv = xr[j];
            a0 += xv.x * e0[4 * j + 0]; a1 += xv.y * e0[4 * j + 1];
            a2 += xv.z * e0[4 * j + 2]; a3 += xv.w * e0[4 * j + 3];
            b0 += xv.x * e1[4 * j + 0]; b1 += xv.y * e1[4 * j + 1];
            b2 += xv.z * e1[4 * j + 2]; b3 += xv.w * e1[4 * j + 3];
        }
        float dot0 = (a0 + a1) + (a2 + a3);
        float dot1 = (b0 + b1) + (b2 + b3);
        float d0 = eknorm[c]     - 2.f * dot0;
        float d1 = eknorm[c + 1] - 2.f * dot1;
        if (d0 < dmin) { dmin = d0; amin = c; }       // strict <: first-index tie-break
        if (d1 < dmin) { dmin = d1; amin = c + 1; }
    }

    idx_s[tid] = amin;
    atomicAdd(&hist[amin], 1);

    // ---- loss partial: |x - e_amin|^2 = xnorm + dmin ----
    float lossv = xnorm + dmin;
    #pragma unroll
    for (int off = 32; off >= 1; off >>= 1) lossv += __shfl_down(lossv, off);
    if ((tid & 63) == 0) red[tid >> 6] = lossv;
    __syncthreads();   // idx_s, hist, red visible

    if (tid == 0) atomicAdd(g_loss, (red[0] + red[1]) + (red[2] + red[3]));
    {
        int c0 = hist[tid], c1 = hist[tid + 256];
        if (c0) atomicAdd(&g_counts[tid], c0);
        if (c1) atomicAdd(&g_counts[tid + 256], c1);
    }

    // ---- quantized: gather from emb (L2-hot), coalesced dword stores ----
    {
        float* qout = out + Q_OFF + (size_t)blockIdx.x * BLOCK * ND;
        #pragma unroll 4
        for (int i = 0; i < 64; ++i) {
            int p = tid + i * BLOCK;
            int r = p >> 6;
            int col = p & 63;
            qout[p] = emb[idx_s[r] * ND + col];
        }
    }

    // ---- encodings: one-hot rows; iteration i == row i, idx uniform ----
    {
        vfloat2* eout = (vfloat2*)(out + ENC_OFF + (size_t)blockIdx.x * BLOCK * NK);
        for (int i = 0; i < BLOCK; ++i) {
            int am = idx_s[i];                  // wave-uniform
            vfloat2 v = {0.f, 0.f};
            if ((am >> 1) == tid) {
                if (am & 1) v.y = 1.f; else v.x = 1.f;
            }
            __builtin_nontemporal_store(v, &eout[(size_t)i * 256 + tid]);
        }
    }
}

__global__ __launch_bounds__(512) void vq_final(const int* __restrict__ g_counts,
                                                const float* __restrict__ g_loss,
                                                float* __restrict__ out) {
    __shared__ float red[8];
    int t = threadIdx.x;
    float p = (float)g_counts[t] * (1.0f / (float)NROWS);
    float h = p * logf(p + 1e-10f);
    #pragma unroll
    for (int off = 32; off >= 1; off >>= 1) h += __shfl_down(h, off);
    if ((t & 63) == 0) red[t >> 6] = h;
    __syncthreads();
    if (t == 0) {
        float s = 0.f;
        #pragma unroll
        for (int i = 0; i < 8; ++i) s += red[i];
        out[PERP_OFF] = expf(-s);
        out[0] = 0.25f * g_loss[0] / (float)(NROWS * ND);
    }
}

extern "C" void kernel_launch(void* const* d_in, const int* in_sizes, int n_in,
                              void* d_out, int out_size, void* d_ws, size_t ws_size,
                              hipStream_t stream) {
    const float* x   = (const float*)d_in[0];
    const float* emb = (const float*)d_in[1];
    float* out = (float*)d_out;

    int*   g_counts = (int*)d_ws;                       // 512 ints
    float* g_loss   = (float*)((char*)d_ws + 2048);     // 1 float
    float* eknorm   = (float*)((char*)d_ws + 4096);     // 512 floats

    // ws re-poisoned to 0xAA before every launch — zero counts+loss (eknorm is
    // fully overwritten by vq_eknorm each call).
    (void)hipMemsetAsync(d_ws, 0, 4096, stream);

    vq_eknorm<<<1, 512, 0, stream>>>(emb, eknorm);
    vq_main<<<NBLOCKS, BLOCK, 0, stream>>>(x, emb, eknorm, out, g_counts, g_loss);
    vq_final<<<1, 512, 0, stream>>>(g_counts, g_loss, out);
}

// Round 5
// 372.896 us; speedup vs baseline: 1.9868x; 1.9868x over previous
//
#include <hip/hip_runtime.h>
#include <math.h>

// VQ-VAE eval forward via MFMA GEMM.
// inputs: [128,1024,64] fp32, embedding: [512,64] fp32
// out: loss[1] | quantized[8388608] | perplexity[1] | encodings[67108864]
//
// R5: distances via bf16 hi/lo-split MFMA (4 cross-terms = fp32-grade ~1.3e-4),
// top-2 tracking + exact fp32 rescore for rows with gap < MARGIN.
// E pre-transformed to B-fragment order in ws (L2-hot coalesced loads).
// Sweep ~15 us MFMA; kernel should be bound by the 302 MB output stores.

#define NK 512
#define ND 64
#define NROWS 131072
#define ROWS_PB 64
#define BLOCK 256
#define NBLOCKS (NROWS / ROWS_PB)   // 2048
#define NTILES 32                   // 32 code-tiles of 16
#define XSTRIDE 68                  // lds_x row stride (floats): 16B-aligned, 2-way-bank-free
#define MARGIN 0.02f                // ~150x the hi/lo error bound

#define Q_OFF    1
#define PERP_OFF 8388609
#define ENC_OFF  8388610

typedef float vf2 __attribute__((ext_vector_type(2)));
typedef float vf4 __attribute__((ext_vector_type(4)));
typedef short vs8 __attribute__((ext_vector_type(8)));

__device__ __forceinline__ unsigned short bf16_rne(float v) {
    union { float f; unsigned int u; } a; a.f = v;
    return (unsigned short)((a.u + 0x7FFFu + ((a.u >> 16) & 1u)) >> 16);
}
__device__ __forceinline__ float bf16_to_f(unsigned short s) {
    union { unsigned int u; float f; } a; a.u = ((unsigned int)s) << 16;
    return a.f;
}

// ---- prep: E -> B-fragment stream (hi/lo bf16) + |e|^2 fp32 ----
// frag f per tile t: f0={eh,k0-31} f1={eh,k32-63} f2={el,k0-31} f3={el,k32-63}
// B-frag lane map (16x16x32): n = lane&15 (code-in-tile), k = (lane>>4)*8 + j
__global__ __launch_bounds__(64) void vq_prep(const float* __restrict__ emb,
                                              float* __restrict__ eknorm,
                                              unsigned int* __restrict__ efrag) {
    const int t = blockIdx.x;        // tile
    const int l = threadIdx.x;       // lane
    const int c = t * 16 + (l & 15);
    const int quad = l >> 4;
    #pragma unroll
    for (int f = 0; f < 4; ++f) {
        const int kbase = (f & 1) * 32 + quad * 8;
        unsigned int w[4];
        #pragma unroll
        for (int d = 0; d < 4; ++d) {
            float v0 = emb[c * ND + kbase + 2 * d];
            float v1 = emb[c * ND + kbase + 2 * d + 1];
            unsigned short h0 = bf16_rne(v0), h1 = bf16_rne(v1);
            unsigned short l0 = bf16_rne(v0 - bf16_to_f(h0));
            unsigned short l1 = bf16_rne(v1 - bf16_to_f(h1));
            unsigned short e0 = (f < 2) ? h0 : l0;
            unsigned short e1 = (f < 2) ? h1 : l1;
            w[d] = (unsigned int)e0 | ((unsigned int)e1 << 16);
        }
        unsigned int* dst = efrag + ((size_t)(t * 4 + f) * 64 + l) * 4;
        dst[0] = w[0]; dst[1] = w[1]; dst[2] = w[2]; dst[3] = w[3];
    }
    if (quad == 0) {   // threads 0..15: eknorm for this tile's 16 codes
        const vf4* er = (const vf4*)(emb + c * ND);
        float s0 = 0.f, s1 = 0.f, s2 = 0.f, s3 = 0.f;
        #pragma unroll
        for (int j = 0; j < 16; ++j) {
            vf4 v = er[j];
            s0 += v.x * v.x; s1 += v.y * v.y; s2 += v.z * v.z; s3 += v.w * v.w;
        }
        eknorm[c] = (s0 + s1) + (s2 + s3);
    }
}

__global__ __launch_bounds__(BLOCK) void vq_main(const float* __restrict__ x,
                                                 const float* __restrict__ emb,
                                                 const float* __restrict__ eknorm,
                                                 const unsigned int* __restrict__ efrag,
                                                 float* __restrict__ out,
                                                 int* __restrict__ g_counts,
                                                 float* __restrict__ g_loss) {
    __shared__ float lds_x[ROWS_PB * XSTRIDE];   // 64 rows x 64 fp32 (stride 68)
    __shared__ float ek_lds[NK];
    __shared__ float d1s[ROWS_PB], d2s[ROWS_PB];
    __shared__ int   i1s[ROWS_PB], i2s[ROWS_PB];
    __shared__ int   idx_s[ROWS_PB];
    __shared__ float red[4];

    const int tid  = threadIdx.x;
    const int wave = tid >> 6;
    const int lane = tid & 63;
    const int col  = lane & 15;
    const int quad = lane >> 4;

    // ---- stage X tile (coalesced float4) + eknorm into LDS ----
    {
        const vf4* xp = (const vf4*)(x + (size_t)blockIdx.x * ROWS_PB * ND);
        #pragma unroll
        for (int i = 0; i < 4; ++i) {
            int e4 = tid + i * BLOCK;          // float4 index 0..1023
            int r  = e4 >> 4;                  // 16 float4 per row
            int c4 = (e4 & 15) * 4;
            *(vf4*)&lds_x[r * XSTRIDE + c4] = xp[e4];
        }
        ek_lds[tid] = eknorm[tid];
        ek_lds[tid + 256] = eknorm[tid + 256];
    }
    __syncthreads();

    // ---- build A-fragments (hi/lo) from my wave's 16 rows ----
    // A map: m = lane&15 (row-in-tile), k = quad*8 + j
    const int arow = wave * 16 + col;
    vs8 ah0, ah1, al0, al1;
    {
        const float* xr = &lds_x[arow * XSTRIDE];
        #pragma unroll
        for (int j = 0; j < 8; ++j) {
            float va = xr[quad * 8 + j];
            float vb = xr[32 + quad * 8 + j];
            unsigned short ha = bf16_rne(va);
            unsigned short hb = bf16_rne(vb);
            ah0[j] = (short)ha; al0[j] = (short)bf16_rne(va - bf16_to_f(ha));
            ah1[j] = (short)hb; al1[j] = (short)bf16_rne(vb - bf16_to_f(hb));
        }
    }

    // ---- sweep 32 code-tiles: 8 MFMA each, top-2 tracking ----
    float d1[4], d2[4];
    int   i1[4], i2[4];
    #pragma unroll
    for (int r = 0; r < 4; ++r) { d1[r] = INFINITY; d2[r] = INFINITY; i1[r] = 0x7FFFFFFF; i2[r] = 0x7FFFFFFF; }

    const vs8* bbase = (const vs8*)efrag;
    vs8 b0 = bbase[(0 * 4 + 0) * 64 + lane];
    vs8 b1 = bbase[(0 * 4 + 1) * 64 + lane];
    vs8 b2 = bbase[(0 * 4 + 2) * 64 + lane];
    vs8 b3 = bbase[(0 * 4 + 3) * 64 + lane];

    for (int t = 0; t < NTILES; ++t) {
        vs8 n0, n1, n2, n3;
        if (t + 1 < NTILES) {
            n0 = bbase[((t + 1) * 4 + 0) * 64 + lane];
            n1 = bbase[((t + 1) * 4 + 1) * 64 + lane];
            n2 = bbase[((t + 1) * 4 + 2) * 64 + lane];
            n3 = bbase[((t + 1) * 4 + 3) * 64 + lane];
        }
        vf4 acc = {0.f, 0.f, 0.f, 0.f};
        acc = __builtin_amdgcn_mfma_f32_16x16x32_bf16(ah0, b0, acc, 0, 0, 0);
        acc = __builtin_amdgcn_mfma_f32_16x16x32_bf16(ah1, b1, acc, 0, 0, 0);
        acc = __builtin_amdgcn_mfma_f32_16x16x32_bf16(al0, b0, acc, 0, 0, 0);
        acc = __builtin_amdgcn_mfma_f32_16x16x32_bf16(al1, b1, acc, 0, 0, 0);
        acc = __builtin_amdgcn_mfma_f32_16x16x32_bf16(ah0, b2, acc, 0, 0, 0);
        acc = __builtin_amdgcn_mfma_f32_16x16x32_bf16(ah1, b3, acc, 0, 0, 0);
        acc = __builtin_amdgcn_mfma_f32_16x16x32_bf16(al0, b2, acc, 0, 0, 0);
        acc = __builtin_amdgcn_mfma_f32_16x16x32_bf16(al1, b3, acc, 0, 0, 0);

        const float ek = ek_lds[t * 16 + col];
        const int cidx = t * 16 + col;
        #pragma unroll
        for (int r = 0; r < 4; ++r) {
            float d = ek - 2.f * acc[r];
            bool lt1 = d < d1[r];
            bool lt2 = d < d2[r];
            float nd2 = lt1 ? d1[r] : (lt2 ? d : d2[r]);
            int   ni2 = lt1 ? i1[r] : (lt2 ? cidx : i2[r]);
            d2[r] = nd2; i2[r] = ni2;
            d1[r] = lt1 ? d : d1[r];
            i1[r] = lt1 ? cidx : i1[r];
        }
        b0 = n0; b1 = n1; b2 = n2; b3 = n3;
    }

    // ---- butterfly-merge top-2 across the 16 lanes holding each row ----
    #pragma unroll
    for (int m = 8; m >= 1; m >>= 1) {
        #pragma unroll
        for (int r = 0; r < 4; ++r) {
            float od1 = __shfl_xor(d1[r], m);
            int   oi1 = __shfl_xor(i1[r], m);
            float od2 = __shfl_xor(d2[r], m);
            int   oi2 = __shfl_xor(i2[r], m);
            bool aF = (d1[r] < od1) || (d1[r] == od1 && i1[r] < oi1);
            float n1 = aF ? d1[r] : od1;  int ni1 = aF ? i1[r] : oi1;
            float ca = aF ? od1 : d1[r];  int cia = aF ? oi1 : i1[r];
            float cb = aF ? d2[r] : od2;  int cib = aF ? i2[r] : oi2;
            bool bF = (cb < ca) || (cb == ca && cib < cia);
            float n2 = bF ? cb : ca;      int ni2 = bF ? cib : cia;
            d1[r] = n1; i1[r] = ni1; d2[r] = n2; i2[r] = ni2;
        }
    }
    if (col == 0) {
        #pragma unroll
        for (int r = 0; r < 4; ++r) {
            int lr = wave * 16 + quad * 4 + r;   // C layout: row = quad*4 + reg
            d1s[lr] = d1[r]; i1s[lr] = i1[r];
            d2s[lr] = d2[r]; i2s[lr] = i2[r];
        }
    }
    __syncthreads();

    // ---- rescore near-ties in exact fp32; commit argmin + histogram ----
    if (tid < ROWS_PB) {
        int am = i1s[tid];
        if (d2s[tid] - d1s[tid] < MARGIN) {
            int ia = i1s[tid], ib = i2s[tid];
            const float* xr = &lds_x[tid * XSTRIDE];
            float da, db;
            {
                const vf4* er = (const vf4*)(emb + ia * ND);
                float s0 = 0.f, s1 = 0.f, s2 = 0.f, s3 = 0.f;
                #pragma unroll
                for (int j = 0; j < 16; ++j) {
                    vf4 v = er[j];
                    s0 += xr[4 * j] * v.x; s1 += xr[4 * j + 1] * v.y;
                    s2 += xr[4 * j + 2] * v.z; s3 += xr[4 * j + 3] * v.w;
                }
                da = ek_lds[ia] - 2.f * ((s0 + s1) + (s2 + s3));
            }
            {
                const vf4* er = (const vf4*)(emb + ib * ND);
                float s0 = 0.f, s1 = 0.f, s2 = 0.f, s3 = 0.f;
                #pragma unroll
                for (int j = 0; j < 16; ++j) {
                    vf4 v = er[j];
                    s0 += xr[4 * j] * v.x; s1 += xr[4 * j + 1] * v.y;
                    s2 += xr[4 * j + 2] * v.z; s3 += xr[4 * j + 3] * v.w;
                }
                db = ek_lds[ib] - 2.f * ((s0 + s1) + (s2 + s3));
            }
            // numpy first-index semantics on exact distances
            am = ((db < da) || (db == da && ib < ia)) ? ib : ia;
        }
        idx_s[tid] = am;
        atomicAdd(&g_counts[am], 1);
    }
    __syncthreads();

    // ---- quantized gather + exact elementwise loss ----
    float lacc = 0.f;
    {
        float* qout = out + Q_OFF + (size_t)blockIdx.x * ROWS_PB * ND;
        #pragma unroll 4
        for (int i = 0; i < 16; ++i) {
            int p = tid + i * BLOCK;
            int r = p >> 6;
            int c = p & 63;
            float q = emb[idx_s[r] * ND + c];     // wave-uniform row, coalesced
            float xv = lds_x[r * XSTRIDE + c];
            qout[p] = q;
            float dlt = q - xv;
            lacc += dlt * dlt;
        }
    }
    #pragma unroll
    for (int off = 32; off >= 1; off >>= 1) lacc += __shfl_down(lacc, off);
    if (lane == 0) red[wave] = lacc;
    __syncthreads();
    if (tid == 0) atomicAdd(g_loss, (red[0] + red[1]) + (red[2] + red[3]));

    // ---- encodings: one-hot rows, vf2 nontemporal stores (base is 8B-aligned) ----
    {
        vf2* eout = (vf2*)(out + ENC_OFF) + (size_t)blockIdx.x * ROWS_PB * NK / 2;
        #pragma unroll 4
        for (int i = 0; i < 64; ++i) {
            int p = tid + i * BLOCK;
            int r = p >> 8;          // 256 vf2 per row
            int c2 = p & 255;
            int am = idx_s[r];
            vf2 v = {0.f, 0.f};
            if ((am >> 1) == c2) {
                if (am & 1) v.y = 1.f; else v.x = 1.f;
            }
            __builtin_nontemporal_store(v, &eout[p]);
        }
    }
}

__global__ __launch_bounds__(512) void vq_final(const int* __restrict__ g_counts,
                                                const float* __restrict__ g_loss,
                                                float* __restrict__ out) {
    __shared__ float red[8];
    int t = threadIdx.x;
    float p = (float)g_counts[t] * (1.0f / (float)NROWS);
    float h = p * logf(p + 1e-10f);
    #pragma unroll
    for (int off = 32; off >= 1; off >>= 1) h += __shfl_down(h, off);
    if ((t & 63) == 0) red[t >> 6] = h;
    __syncthreads();
    if (t == 0) {
        float s = 0.f;
        #pragma unroll
        for (int i = 0; i < 8; ++i) s += red[i];
        out[PERP_OFF] = expf(-s);
        out[0] = 0.25f * g_loss[0] / (float)(NROWS * ND);
    }
}

extern "C" void kernel_launch(void* const* d_in, const int* in_sizes, int n_in,
                              void* d_out, int out_size, void* d_ws, size_t ws_size,
                              hipStream_t stream) {
    const float* x   = (const float*)d_in[0];
    const float* emb = (const float*)d_in[1];
    float* out = (float*)d_out;

    int*          g_counts = (int*)d_ws;                         // 512 ints
    float*        g_loss   = (float*)((char*)d_ws + 2048);       // 1 float
    float*        eknorm   = (float*)((char*)d_ws + 4096);       // 512 floats
    unsigned int* efrag    = (unsigned int*)((char*)d_ws + 8192);// 128 KB frag stream

    // ws re-poisoned to 0xAA before every launch — zero counts+loss
    // (eknorm/efrag are fully overwritten by vq_prep each call).
    (void)hipMemsetAsync(d_ws, 0, 4096, stream);

    vq_prep<<<NTILES, 64, 0, stream>>>(emb, eknorm, efrag);
    vq_main<<<NBLOCKS, BLOCK, 0, stream>>>(x, emb, eknorm, efrag, out, g_counts, g_loss);
    vq_final<<<1, 512, 0, stream>>>(g_counts, g_loss, out);
}